// Round 10
// baseline (80.575 us; speedup 1.0000x reference)
//
#include <hip/hip_runtime.h>
#include <hip/hip_bf16.h>

// NF4 double-quant dequantize + x @ W^T — barrier-free fragment-direct design.
// Key insight: packed layout is already MFMA-fragment-ready (lane l&15 = W row,
// (l>>4)*8 k-elems = 4 consecutive packed words = one i32x4 load). No LDS, no
// __syncthreads. Each wave owns 16 W rows x K/2, 4-deep register pipeline.
// x: [32][4096] f32 (pre-converted to bf16 in ws by xconv_kernel).
// out: [32][14336] f32; KSPLIT=2 -> exactly 2 atomicAdd contributors/output
// (commutative -> bitwise deterministic; validated r8).

#define OUT_D 14336
#define IN_D  4096
#define B_D   32

typedef __attribute__((ext_vector_type(4))) float f32x4;
typedef __attribute__((ext_vector_type(4))) int   i32x4;
typedef __bf16 bf16x8 __attribute__((ext_vector_type(8)));
typedef __bf16 bf16x4 __attribute__((ext_vector_type(4)));
using u16 = unsigned short;

__global__ __launch_bounds__(256) void xconv_kernel(const float* __restrict__ x,
                                                    u16* __restrict__ xb) {
    int i = (blockIdx.x * 256 + threadIdx.x) * 4;
    f32x4 v = *reinterpret_cast<const f32x4*>(x + i);
    bf16x4 h;
    h[0] = (__bf16)v[0]; h[1] = (__bf16)v[1];
    h[2] = (__bf16)v[2]; h[3] = (__bf16)v[3];
    *reinterpret_cast<bf16x4*>(xb + i) = h;
}

__global__ __launch_bounds__(256) void nf4_kernel(
    const u16*  __restrict__ xb,        // [32][4096] bf16 (from ws)
    const int*  __restrict__ packed,    // [N/2] one byte per int32
    const float* __restrict__ absmax,   // [NB]
    const float* __restrict__ code,     // [NB]
    const float* __restrict__ offset,   // [NB]
    const float* __restrict__ g_absmax, // [NG]
    const float* __restrict__ g_code,   // [NG]
    float* __restrict__ out)            // [32][14336] f32 (pre-zeroed)
{
    const int lane = threadIdx.x & 63;
    const int wave = threadIdx.x >> 6;
    const int frow = lane & 15;              // W-row within wave tile; A-row (batch)
    const int fk   = lane >> 4;              // 0..3 k-subchunk
    const int o    = blockIdx.x * 64 + wave * 16 + frow;  // this lane's W row
    const int kz   = blockIdx.y;             // K-split half

    const int* wp  = packed + o * (IN_D / 2) + kz * (IN_D / 4) + fk * 4;
    const u16* xlo = xb + frow * IN_D + kz * (IN_D / 2) + fk * 8;   // batch 0-15
    const u16* xhi = xlo + 16 * IN_D;                               // batch 16-31
    const int  sb  = o * 64 + kz * 32;       // scale-block base
    const int  gb  = o * 16 + kz * 8;        // group-scale base

    f32x4 acc0 = {0.f, 0.f, 0.f, 0.f};      // D rows 0-15 (batch) x col o
    f32x4 acc1 = {0.f, 0.f, 0.f, 0.f};      // D rows 16-31

    i32x4  w0, w1, w2, w3;                   // W packed, 4-deep
    bf16x8 xl0, xl1, xl2, xl3;               // x A-frag low half, 4-deep
    bf16x8 xh0, xh1, xh2, xh3;               // x A-frag high half
    float cs0, noc0, cs1, noc1, csn0, nocn0, csn1, nocn1;

#define ISSUE(J, S) \
    w##J  = *reinterpret_cast<const i32x4*>(wp + (S) * 16); \
    xl##J = *reinterpret_cast<const bf16x8*>(xlo + (S) * 32); \
    xh##J = *reinterpret_cast<const bf16x8*>(xhi + (S) * 32);

#define LOADSC(CS, NOC, BLK) { \
    float am = absmax[sb + (BLK)], cd = code[sb + (BLK)], of = offset[sb + (BLK)]; \
    float ga = g_absmax[gb + ((BLK) >> 2)], gc = g_code[gb + ((BLK) >> 2)]; \
    CS = (am * ga) / (cd * gc); NOC = -of * CS; }

#define PHASE(J, CS, NOC) { \
    bf16x8 bf; \
    _Pragma("unroll") \
    for (int q = 0; q < 4; ++q) { \
        int w = w##J[q]; \
        bf[2 * q]     = (__bf16)fmaf((float)(w & 15),        CS, NOC); \
        bf[2 * q + 1] = (__bf16)fmaf((float)((w >> 4) & 15), CS, NOC); \
    } \
    acc0 = __builtin_amdgcn_mfma_f32_16x16x32_bf16(xl##J, bf, acc0, 0, 0, 0); \
    acc1 = __builtin_amdgcn_mfma_f32_16x16x32_bf16(xh##J, bf, acc1, 0, 0, 0); }

    // prologue: steps 0-3 in flight, scales for blocks 0,1
    ISSUE(0, 0) ISSUE(1, 1) ISSUE(2, 2) ISSUE(3, 3)
    LOADSC(cs0, noc0, 0) LOADSC(cs1, noc1, 1)

    // 64 k-steps of 32; groups of 4 with reissue 4 ahead; last group peeled
    for (int g = 0; g < 15; ++g) {
        const int s4 = g * 4 + 4;
        LOADSC(csn0, nocn0, 2 * g + 2)       // next group's scales (in shadow)
        LOADSC(csn1, nocn1, 2 * g + 3)
        PHASE(0, cs0, noc0)  ISSUE(0, s4 + 0)
        PHASE(1, cs0, noc0)  ISSUE(1, s4 + 1)
        PHASE(2, cs1, noc1)  ISSUE(2, s4 + 2)
        PHASE(3, cs1, noc1)  ISSUE(3, s4 + 3)
        cs0 = csn0; noc0 = nocn0; cs1 = csn1; noc1 = nocn1;
    }
    PHASE(0, cs0, noc0) PHASE(1, cs0, noc0)
    PHASE(2, cs1, noc1) PHASE(3, cs1, noc1)

    // epilogue: D col = lane&15 -> out col o; row = fk*4 + i (batch)
    const int r0 = fk * 4;
    #pragma unroll
    for (int i = 0; i < 4; ++i) {
        atomicAdd(&out[(r0 + i) * OUT_D + o],      acc0[i]);
        atomicAdd(&out[(r0 + 16 + i) * OUT_D + o], acc1[i]);
    }
#undef ISSUE
#undef LOADSC
#undef PHASE
}

extern "C" void kernel_launch(void* const* d_in, const int* in_sizes, int n_in,
                              void* d_out, int out_size, void* d_ws, size_t ws_size,
                              hipStream_t stream) {
    const void* px = nullptr;
    const void* ppk = nullptr;
    const void* trio[3] = {nullptr, nullptr, nullptr};
    const void* pair[2] = {nullptr, nullptr};
    int ntrio = 0, npair = 0;
    const int SZ_X   = B_D * IN_D;            // 131072
    const int SZ_PK  = OUT_D * (IN_D / 2);    // 29360128
    const int SZ_NB  = OUT_D * (IN_D / 64);   // 917504
    const int SZ_NG  = OUT_D * (IN_D / 256);  // 229376
    for (int i = 0; i < n_in; ++i) {
        int s = in_sizes[i];
        if (s == SZ_X) px = d_in[i];
        else if (s == SZ_PK) ppk = d_in[i];
        else if (s == SZ_NB) { if (ntrio < 3) trio[ntrio++] = d_in[i]; }
        else if (s == SZ_NG) { if (npair < 2) pair[npair++] = d_in[i]; }
    }
    if (!px || !ppk || ntrio != 3 || npair != 2) {
        px = d_in[0]; ppk = d_in[1];
        trio[0] = d_in[2]; trio[1] = d_in[3]; trio[2] = d_in[4];
        pair[0] = d_in[5]; pair[1] = d_in[6];
    }

    u16* xbf = (u16*)d_ws;                    // 256 KB of ws for bf16 x

    // x f32 -> bf16 (fragment loads become single 16B reads)
    xconv_kernel<<<dim3(SZ_X / 1024), dim3(256), 0, stream>>>((const float*)px, xbf);

    // zero-init output; kernel accumulates (2 deterministic contributions)
    hipMemsetAsync(d_out, 0, (size_t)out_size * sizeof(float), stream);

    nf4_kernel<<<dim3(OUT_D / 64, 2), dim3(256), 0, stream>>>(
        xbf, (const int*)ppk,
        (const float*)trio[0], (const float*)trio[1], (const float*)trio[2],
        (const float*)pair[0], (const float*)pair[1],
        (float*)d_out);
}

// Round 11
// 57.511 us; speedup vs baseline: 1.4010x; 1.4010x over previous
//
#include <hip/hip_runtime.h>
#include <hip/hip_bf16.h>

// NF4 double-quant dequantize + x @ W^T — fragment-direct, TLP-first design.
// packed layout is MFMA-fragment-ready: lane (l&15)=W-row, (l>>4)=k-subchunk
// -> one i32x4 load per B-fragment, dequant in-register, no LDS staging, no
// staging barriers. 4 waves/block split K; 1792 blocks (7 waves/SIMD) hide
// HBM latency by TLP alone (r8/r10 lesson: compiler collapses deep register
// pipelines; occupancy was the missing lever).
// x: [32][4096] f32 -> pre-converted to bf16 in ws. out: [32][14336] f32.
// Cross-wave: fixed-order LDS reduce; cross-block(y): 2 atomicAdd contributors
// (commutative -> deterministic).

#define OUT_D 14336
#define IN_D  4096
#define B_D   32

typedef __attribute__((ext_vector_type(4))) float f32x4;
typedef __attribute__((ext_vector_type(4))) int   i32x4;
typedef __bf16 bf16x8 __attribute__((ext_vector_type(8)));
typedef __bf16 bf16x4 __attribute__((ext_vector_type(4)));
using u16 = unsigned short;

__global__ __launch_bounds__(256) void xconv_kernel(const float* __restrict__ x,
                                                    u16* __restrict__ xb) {
    int i = (blockIdx.x * 256 + threadIdx.x) * 4;
    f32x4 v = *reinterpret_cast<const f32x4*>(x + i);
    bf16x4 h;
    h[0] = (__bf16)v[0]; h[1] = (__bf16)v[1];
    h[2] = (__bf16)v[2]; h[3] = (__bf16)v[3];
    *reinterpret_cast<bf16x4*>(xb + i) = h;
}

__global__ __launch_bounds__(256, 8) void nf4_kernel(
    const u16*  __restrict__ xb,        // [32][4096] bf16 (ws)
    const int*  __restrict__ packed,    // [N/2] one byte per int32
    const float* __restrict__ absmax,   // [NB]
    const float* __restrict__ code,     // [NB]
    const float* __restrict__ offset,   // [NB]
    const float* __restrict__ g_absmax, // [NG]
    const float* __restrict__ g_code,   // [NG]
    float* __restrict__ out)            // [32][14336] f32 (pre-zeroed)
{
    __shared__ float red[3][64][8];      // waves 1-3 partials

    const int lane = threadIdx.x & 63;
    const int wv   = threadIdx.x >> 6;   // wave id = k-quarter
    const int frow = lane & 15;          // W-row in tile; also batch row for A
    const int fk   = lane >> 4;          // 0..3 k-subchunk of the MFMA frag
    const int o    = blockIdx.x * 16 + frow;   // this lane's W row / out col
    const int kz   = blockIdx.y;               // K half

    // this wave's k-range: 512 elements = 16 steps of 32
    const int ke   = kz * 2048 + wv * 512;     // element base
    const int* wp  = packed + o * (IN_D / 2) + ke / 2 + fk * 4;
    const u16* xlo = xb + frow * IN_D + ke + fk * 8;   // batch rows 0-15
    const u16* xhi = xlo + 16 * IN_D;                  // batch rows 16-31
    const int  sb  = o * 64 + ke / 64;          // 8 scale blocks for this wave
    const int  gb  = o * 16 + ke / 256;         // 2 groups

    f32x4 acc0 = {0.f, 0.f, 0.f, 0.f};   // batch rows 0-15  x col o
    f32x4 acc1 = {0.f, 0.f, 0.f, 0.f};   // batch rows 16-31 x col o

    #pragma unroll
    for (int blk = 0; blk < 8; ++blk) {   // 64-elem scale blocks
        const float am = absmax[sb + blk], cd = code[sb + blk];
        const float of = offset[sb + blk];
        const float ga = g_absmax[gb + (blk >> 2)], gc = g_code[gb + (blk >> 2)];
        const float cs  = (am * ga) / (cd * gc);
        const float noc = -of * cs;
        #pragma unroll
        for (int h = 0; h < 2; ++h) {     // 2 k-steps of 32 per block
            const int s = blk * 2 + h;
            i32x4  w  = *reinterpret_cast<const i32x4*>(wp + s * 16);
            bf16x8 xl = *reinterpret_cast<const bf16x8*>(xlo + s * 32);
            bf16x8 xh = *reinterpret_cast<const bf16x8*>(xhi + s * 32);
            bf16x8 bf;
            #pragma unroll
            for (int q = 0; q < 4; ++q) {
                int ww = w[q];
                bf[2 * q]     = (__bf16)fmaf((float)(ww & 15),        cs, noc);
                bf[2 * q + 1] = (__bf16)fmaf((float)((ww >> 4) & 15), cs, noc);
            }
            acc0 = __builtin_amdgcn_mfma_f32_16x16x32_bf16(xl, bf, acc0, 0, 0, 0);
            acc1 = __builtin_amdgcn_mfma_f32_16x16x32_bf16(xh, bf, acc1, 0, 0, 0);
        }
    }

    // ---- fixed-order cross-wave reduce (deterministic) ----
    if (wv != 0) {
        #pragma unroll
        for (int i = 0; i < 4; ++i) {
            red[wv - 1][lane][i]     = acc0[i];
            red[wv - 1][lane][i + 4] = acc1[i];
        }
    }
    __syncthreads();
    if (wv == 0) {
        const int r0 = fk * 4;
        #pragma unroll
        for (int i = 0; i < 4; ++i) {
            float v0 = ((acc0[i] + red[0][lane][i]) + red[1][lane][i]) + red[2][lane][i];
            float v1 = ((acc1[i] + red[0][lane][i + 4]) + red[1][lane][i + 4]) + red[2][lane][i + 4];
            atomicAdd(&out[(r0 + i) * OUT_D + o],      v0);   // 2 contributors (y=0,1)
            atomicAdd(&out[(r0 + 16 + i) * OUT_D + o], v1);
        }
    }
}

extern "C" void kernel_launch(void* const* d_in, const int* in_sizes, int n_in,
                              void* d_out, int out_size, void* d_ws, size_t ws_size,
                              hipStream_t stream) {
    const void* px = nullptr;
    const void* ppk = nullptr;
    const void* trio[3] = {nullptr, nullptr, nullptr};
    const void* pair[2] = {nullptr, nullptr};
    int ntrio = 0, npair = 0;
    const int SZ_X   = B_D * IN_D;            // 131072
    const int SZ_PK  = OUT_D * (IN_D / 2);    // 29360128
    const int SZ_NB  = OUT_D * (IN_D / 64);   // 917504
    const int SZ_NG  = OUT_D * (IN_D / 256);  // 229376
    for (int i = 0; i < n_in; ++i) {
        int s = in_sizes[i];
        if (s == SZ_X) px = d_in[i];
        else if (s == SZ_PK) ppk = d_in[i];
        else if (s == SZ_NB) { if (ntrio < 3) trio[ntrio++] = d_in[i]; }
        else if (s == SZ_NG) { if (npair < 2) pair[npair++] = d_in[i]; }
    }
    if (!px || !ppk || ntrio != 3 || npair != 2) {
        px = d_in[0]; ppk = d_in[1];
        trio[0] = d_in[2]; trio[1] = d_in[3]; trio[2] = d_in[4];
        pair[0] = d_in[5]; pair[1] = d_in[6];
    }

    u16* xbf = (u16*)d_ws;                    // 256 KB of ws: bf16 x

    xconv_kernel<<<dim3(SZ_X / 1024), dim3(256), 0, stream>>>((const float*)px, xbf);
    hipMemsetAsync(d_out, 0, (size_t)out_size * sizeof(float), stream);

    nf4_kernel<<<dim3(OUT_D / 16, 2), dim3(256), 0, stream>>>(
        xbf, (const int*)ppk,
        (const float*)trio[0], (const float*)trio[1], (const float*)trio[2],
        (const float*)pair[0], (const float*)pair[1],
        (float*)d_out);
}

// Round 12
// 44.330 us; speedup vs baseline: 1.8176x; 1.2974x over previous
//
#include <hip/hip_runtime.h>
#include <hip/hip_bf16.h>

// NF4 double-quant dequantize + x @ W^T
// r12: r9's dbuf-LDS + prefetch structure, re-parameterized for co-residency:
// KC=128 + KSPLIT=2 -> 34.8 KB LDS -> 4 blocks/CU (was 1.75). Per-chunk
// barrier drains are covered by co-resident blocks (m114 mechanism).
// Packed staging made per-instruction coalesced (instr j = 128B/row-group,
// j == scale-block index within chunk).
// x: [32][4096] f32; out: [32][14336] f32 (harness dtype pinning r5-r7).
// KSPLIT=2 -> exactly 2 atomicAdd contributors/output (deterministic, r8).

#define OUT_D 14336
#define IN_D  4096
#define B_D   32
#define KC    128                  // k-chunk per LDS stage
#define OTILE 32                   // W rows per block
#define KSPLIT 2
#define CHUNKS (IN_D / KC / KSPLIT)  // 16 per block
#define LSTRIDE 136                // bf16 elems per LDS row (128 + 8 pad)

typedef __attribute__((ext_vector_type(4))) float f32x4;
typedef __attribute__((ext_vector_type(4))) int   i32x4;
typedef __bf16 bf16x8 __attribute__((ext_vector_type(8)));
typedef __bf16 bf16x4 __attribute__((ext_vector_type(4)));
using u16 = unsigned short;

__global__ __launch_bounds__(256, 4) void nf4_kernel(
    const float* __restrict__ x,        // [32][4096] f32
    const int*  __restrict__ packed,    // [N/2] one byte per int32
    const float* __restrict__ absmax,   // [NB]
    const float* __restrict__ code,     // [NB]
    const float* __restrict__ offset,   // [NB]
    const float* __restrict__ g_absmax, // [NG]
    const float* __restrict__ g_code,   // [NG]
    float* __restrict__ out)            // [32][14336] f32 (pre-zeroed)
{
    __shared__ u16 wlds[2][OTILE * LSTRIDE];
    __shared__ u16 xlds[2][B_D * LSTRIDE];

    const int t      = threadIdx.x;
    const int o_base = blockIdx.x * OTILE;
    const int kz     = blockIdx.y;           // K half

    // staging roles: 8 threads per W row
    const int wrow = t >> 3;        // 0..31
    const int wseg = t & 7;         // 0..7
    const int o    = o_base + wrow;

    // mfma roles
    const int wave   = t >> 6;
    const int lane   = t & 63;
    const int m_base = (wave & 1) * 16;
    const int n_base = (wave >> 1) * 16;
    const int frow   = lane & 15;
    const int kk     = (lane >> 4) * 8;

    const int*   pbase = packed + o * (IN_D / 2) + kz * (IN_D / 4);
    const float* xbase = x + kz * (IN_D / 2);
    const int    sb    = o * 64 + kz * 32;   // scale-block base for this k-half
    const int    gb    = o * 16;             // group base (full-row indexing)

    f32x4 acc = {0.f, 0.f, 0.f, 0.f};

    i32x4 pkA[2], pkB[2];
    f32x4 pxA[4], pxB[4];
    float csA[2], nocA[2], csB[2], nocB[2];

    // packed: chunk C words [C*64, C*64+64); instr j reads 16B at
    // (j*8+wseg)*4 words -> j=0/1 contiguous 128B per 8-lane row-group,
    // and j == scale-block index within the chunk.
#define LOADPK(DST, C) { \
    DST[0] = *reinterpret_cast<const i32x4*>(pbase + (C) * 64 + wseg * 4); \
    DST[1] = *reinterpret_cast<const i32x4*>(pbase + (C) * 64 + 32 + wseg * 4); }

#define LOADPX(DST, C) { \
    _Pragma("unroll") \
    for (int j2 = 0; j2 < 4; ++j2) { \
        int li = t + j2 * 256; \
        DST[j2] = *reinterpret_cast<const f32x4*>( \
            xbase + (li >> 5) * IN_D + (C) * KC + (li & 31) * 4); } }

#define LOADSC(CS, NOC, C) { \
    _Pragma("unroll") \
    for (int j = 0; j < 2; ++j) { \
        int blk = kz * 32 + (C) * 2 + j;       /* block idx within row */ \
        int bi  = sb + (C) * 2 + j; \
        int gi  = gb + (blk >> 2); \
        float am = absmax[bi], cd = code[bi], of = offset[bi]; \
        float ga = g_absmax[gi], gc = g_code[gi]; \
        CS[j]  = (am * ga) / (cd * gc); \
        NOC[j] = -of * CS[j]; } }

#define BODY(PK, PX, CS, NOC, PKN, PXN, CSN, NOCN, C) { \
    if ((C) + 1 < CHUNKS) { \
        LOADPK(PKN, (C) + 1) \
        LOADPX(PXN, (C) + 1) \
        LOADSC(CSN, NOCN, (C) + 1) \
    } \
    /* dequant W -> wlds[p]; group j covers elems (j*8+wseg)*8..+8 */ \
    _Pragma("unroll") \
    for (int j = 0; j < 2; ++j) { \
        bf16x8 r; \
        _Pragma("unroll") \
        for (int q = 0; q < 4; ++q) { \
            int w = PK[j][q]; \
            r[2 * q]     = (__bf16)fmaf((float)(w & 15),        CS[j], NOC[j]); \
            r[2 * q + 1] = (__bf16)fmaf((float)((w >> 4) & 15), CS[j], NOC[j]); \
        } \
        *reinterpret_cast<bf16x8*>(&wlds[p][wrow * LSTRIDE + (j * 8 + wseg) * 8]) = r; \
    } \
    /* x cvt -> xlds[p] */ \
    _Pragma("unroll") \
    for (int j2 = 0; j2 < 4; ++j2) { \
        int li = t + j2 * 256; \
        bf16x4 h; \
        h[0] = (__bf16)PX[j2][0]; h[1] = (__bf16)PX[j2][1]; \
        h[2] = (__bf16)PX[j2][2]; h[3] = (__bf16)PX[j2][3]; \
        *reinterpret_cast<bf16x4*>(&xlds[p][(li >> 5) * LSTRIDE + (li & 31) * 4]) = h; \
    } \
    __syncthreads(); \
    { \
        const u16* xp = &xlds[p][(m_base + frow) * LSTRIDE + kk]; \
        const u16* wp = &wlds[p][(n_base + frow) * LSTRIDE + kk]; \
        _Pragma("unroll") \
        for (int ks = 0; ks < KC / 32; ++ks) { \
            bf16x8 a = *reinterpret_cast<const bf16x8*>(xp + ks * 32); \
            bf16x8 b = *reinterpret_cast<const bf16x8*>(wp + ks * 32); \
            acc = __builtin_amdgcn_mfma_f32_16x16x32_bf16(a, b, acc, 0, 0, 0); \
        } \
    } \
    p ^= 1; }

    LOADPK(pkA, 0)
    LOADPX(pxA, 0)
    LOADSC(csA, nocA, 0)

    int p = 0;
    for (int ic = 0; ic < CHUNKS; ic += 2) {
        BODY(pkA, pxA, csA, nocA, pkB, pxB, csB, nocB, ic)
        BODY(pkB, pxB, csB, nocB, pkA, pxA, csA, nocA, ic + 1)
    }

    // epilogue: D col = lane&15 -> out col; row = (lane>>4)*4+i -> batch.
    // 2 contributors (kz=0,1): commutative -> deterministic.
    const int oc = o_base + n_base + frow;
    const int r0 = m_base + (lane >> 4) * 4;
    #pragma unroll
    for (int i = 0; i < 4; ++i) {
        atomicAdd(&out[(r0 + i) * OUT_D + oc], acc[i]);
    }
#undef LOADPK
#undef LOADPX
#undef LOADSC
#undef BODY
}

extern "C" void kernel_launch(void* const* d_in, const int* in_sizes, int n_in,
                              void* d_out, int out_size, void* d_ws, size_t ws_size,
                              hipStream_t stream) {
    const void* px = nullptr;
    const void* ppk = nullptr;
    const void* trio[3] = {nullptr, nullptr, nullptr};
    const void* pair[2] = {nullptr, nullptr};
    int ntrio = 0, npair = 0;
    const int SZ_X   = B_D * IN_D;            // 131072
    const int SZ_PK  = OUT_D * (IN_D / 2);    // 29360128
    const int SZ_NB  = OUT_D * (IN_D / 64);   // 917504
    const int SZ_NG  = OUT_D * (IN_D / 256);  // 229376
    for (int i = 0; i < n_in; ++i) {
        int s = in_sizes[i];
        if (s == SZ_X) px = d_in[i];
        else if (s == SZ_PK) ppk = d_in[i];
        else if (s == SZ_NB) { if (ntrio < 3) trio[ntrio++] = d_in[i]; }
        else if (s == SZ_NG) { if (npair < 2) pair[npair++] = d_in[i]; }
    }
    if (!px || !ppk || ntrio != 3 || npair != 2) {
        px = d_in[0]; ppk = d_in[1];
        trio[0] = d_in[2]; trio[1] = d_in[3]; trio[2] = d_in[4];
        pair[0] = d_in[5]; pair[1] = d_in[6];
    }

    hipMemsetAsync(d_out, 0, (size_t)out_size * sizeof(float), stream);

    nf4_kernel<<<dim3(OUT_D / OTILE, KSPLIT), dim3(256), 0, stream>>>(
        (const float*)px, (const int*)ppk,
        (const float*)trio[0], (const float*)trio[1], (const float*)trio[2],
        (const float*)pair[0], (const float*)pair[1],
        (float*)d_out);
}